// Round 10
// baseline (73.514 us; speedup 1.0000x reference)
//
#include <hip/hip_runtime.h>
#include <hip/hip_bf16.h>

typedef __bf16 bf16_t;
typedef __bf16 bf16x8 __attribute__((ext_vector_type(8)));
typedef float f32x4 __attribute__((ext_vector_type(4)));
typedef unsigned short u16;
typedef unsigned int u32;
typedef unsigned long long u64;

#define CH    128
#define NTOK  4096
#define DIMH  32

__device__ __forceinline__ float fast_exp2(float x) {
#if __has_builtin(__builtin_amdgcn_exp2f)
  return __builtin_amdgcn_exp2f(x);
#else
  return exp2f(x);
#endif
}

// ===================== Kernel A: QKV projection =====================
// x: [B][128][4096] f32, w: [384][128] f32.
// qs/ks: [bh][n][32] bf16 (q pre-scaled by 32^-0.5*log2e).
// vs: TILED+SWIZZLED [bh][jb][32 d][64 j] bf16 (16B-chunk XOR d&7).
__global__ __launch_bounds__(256)
void qkv_proj(const float* __restrict__ x, const float* __restrict__ w,
              bf16_t* __restrict__ qs, bf16_t* __restrict__ ks, bf16_t* __restrict__ vs)
{
  __shared__ float xs[128][64];
  __shared__ float wt[128][64];
  const int tid = threadIdx.x;
  const int n0 = blockIdx.x * 64;
  const int o0 = blockIdx.y * 64;
  const int b  = blockIdx.z;

  { // stage x tile [128 c][64 n] via float4 (coalesced)
    const float* xb = x + ((size_t)b * CH) * NTOK + n0;
    const int f4 = tid & 15, c0 = tid >> 4;
    #pragma unroll
    for (int p = 0; p < 8; ++p) {
      const int c = p * 16 + c0;
      *(float4*)&xs[c][f4 * 4] = *(const float4*)(xb + (size_t)c * NTOK + f4 * 4);
    }
  }
  { // stage w tile transposed: wt[c][o_local]
    const int o_l = tid & 63, q4 = tid >> 6;
    const float* wrow = w + (size_t)(o0 + o_l) * CH;
    #pragma unroll
    for (int p = 0; p < 8; ++p) {
      const int c4 = p * 4 + q4;
      const float4 v4 = *(const float4*)(wrow + c4 * 4);
      wt[c4*4+0][o_l] = v4.x;
      wt[c4*4+1][o_l] = v4.y;
      wt[c4*4+2][o_l] = v4.z;
      wt[c4*4+3][o_l] = v4.w;
    }
  }
  __syncthreads();

  const int tx = tid & 15, ty = tid >> 4;
  float acc[4][4] = {};
  for (int c = 0; c < 128; ++c) {
    const float4 xv = *(const float4*)&xs[c][tx * 4];
    const float4 wv = *(const float4*)&wt[c][ty * 4];
    const float xa[4] = {xv.x, xv.y, xv.z, xv.w};
    const float wa[4] = {wv.x, wv.y, wv.z, wv.w};
    #pragma unroll
    for (int io = 0; io < 4; ++io)
      #pragma unroll
      for (int in = 0; in < 4; ++in)
        acc[io][in] += wa[io] * xa[in];
  }
  __syncthreads();

  float (*out_s)[65] = (float(*)[65])&xs[0][0];
  #pragma unroll
  for (int io = 0; io < 4; ++io)
    #pragma unroll
    for (int in = 0; in < 4; ++in)
      out_s[ty*4+io][tx*4+in] = acc[io][in];
  __syncthreads();

  const float QSCALE = 0.17677669529663687f * 1.4426950408889634f; // 32^-0.5 * log2(e)
  if (o0 < 256) {
    bf16_t* dst = (o0 < 128) ? qs : ks;
    const float mul = (o0 < 128) ? QSCALE : 1.0f;
    const int obase = o0 & 127;
    #pragma unroll
    for (int p = 0; p < 16; ++p) {
      const int n_l = p * 4 + (tid >> 6);
      const int o_l = tid & 63;
      const int o = obase + o_l;
      const int h = o >> 5, d = o & 31;
      dst[(((size_t)(b*4 + h)) * NTOK + n0 + n_l) * DIMH + d] = (bf16_t)(out_s[o_l][n_l] * mul);
    }
  } else {
    const int obase = o0 - 256;
    const int jb = n0 >> 6;
    #pragma unroll
    for (int p = 0; p < 16; ++p) {
      const int o_l = p * 4 + (tid >> 6);
      const int n_l = tid & 63;
      const int o = obase + o_l;
      const int h = o >> 5, d = o & 31;
      const int jc = n_l >> 3, e = n_l & 7;
      const size_t tilebase = ((size_t)(b*4 + h) * 64 + jb) * 2048;
      vs[tilebase + d*64 + ((jc ^ (d & 7)) * 8) + e] = (bf16_t)out_s[o_l][n_l];
    }
  }
}

// helper: stage one 4KB K-tile + 4KB V-tile into LDS (direct-to-LDS)
__device__ __forceinline__ void stage_tile(const char* kg, const char* vg,
                                           char* lds, int tid)
{
#if __has_builtin(__builtin_amdgcn_global_load_lds)
  __builtin_amdgcn_global_load_lds(
      (const __attribute__((address_space(1))) void*)(kg + tid * 16),
      (__attribute__((address_space(3))) void*)(lds + tid * 16), 16, 0, 0);
  __builtin_amdgcn_global_load_lds(
      (const __attribute__((address_space(1))) void*)(vg + tid * 16),
      (__attribute__((address_space(3))) void*)(lds + 4096 + tid * 16), 16, 0, 0);
#else
  const uint4 a = *(const uint4*)(kg + tid * 16);
  const uint4 b = *(const uint4*)(vg + tid * 16);
  *(uint4*)(lds + tid * 16) = a;
  *(uint4*)(lds + 4096 + tid * 16) = b;
#endif
}

// ===================== Kernel B: flash attention (R5-proven structure) =====================
// Block: 4 waves x 64 i = 256 i-rows (4 Q-frags/wave); grid (8 bh, 16 ic, nsplit).
// Per j-iter: stage next 64j K+V tile into LDS dbuf (global_load_lds); per q:
// S^T = mfma(K,Q) -> online softmax (shfl_xor reduces, defer-max THR=8) ->
// in-register P route (cvt_pk + permlane swaps, HW-validated in R5) ->
// O^T += mfma(V^T,P). T5: s_setprio(1) around MFMA clusters (pure sched hint).
// NOTE: 2-q/launch_bounds(256,8) restructure failed correctness 4x (R6-R9) --
// do not retry without disasm access.
template<int JB_PER>
__global__ __launch_bounds__(256, 4)
void attn_fwd(const bf16_t* __restrict__ qs, const bf16_t* __restrict__ ks,
              const bf16_t* __restrict__ vs, float* __restrict__ Apart,
              float* __restrict__ ml)
{
  __shared__ alignas(16) char kvbuf[2][8192];          // [buf][K 4KB | V 4KB]

  const int bh    = blockIdx.x;   // 0..7 (fastest dim -> one head per XCD)
  const int ic    = blockIdx.y;   // 0..15
  const int split = blockIdx.z;
  const int tid   = threadIdx.x;
  const int wv    = tid >> 6;
  const int lane  = tid & 63;
  const int g = lane >> 4, r = lane & 15;
  const int i_base = ic * 256 + wv * 64;

  const bf16_t* qh = qs + (size_t)bh * NTOK * DIMH;
  const char*   kg = (const char*)(ks + (size_t)bh * NTOK * DIMH);
  const char*   vg = (const char*)(vs + (size_t)bh * NTOK * DIMH);

  // Q B-frags (hoisted): col=i (lane&15), k=d ((lane>>4)*8+e)
  bf16x8 qf[4];
  #pragma unroll
  for (int q = 0; q < 4; ++q)
    qf[q] = *(const bf16x8*)(qh + (size_t)(i_base + 16*q + r) * DIMH + g * 8);

  f32x4 accL[4] = {}, accH[4] = {};
  const f32x4 zero = {0.f, 0.f, 0.f, 0.f};
  float mrun[4] = {-3.0e38f, -3.0e38f, -3.0e38f, -3.0e38f};
  float lrun[4] = {0.f, 0.f, 0.f, 0.f};

  const int jb0 = split * JB_PER;
  stage_tile(kg + (size_t)jb0 * 4096, vg + (size_t)jb0 * 4096, kvbuf[0], tid);

  for (int it = 0; it < JB_PER; ++it) {
    asm volatile("s_waitcnt vmcnt(0)" ::: "memory");
    __builtin_amdgcn_s_barrier();

    if (it + 1 < JB_PER) {
      const size_t off = (size_t)(jb0 + it + 1) * 4096;
      stage_tile(kg + off, vg + off, kvbuf[(it + 1) & 1], tid);
    }

    const char* kb = kvbuf[it & 1];
    const char* vb = kb + 4096;

    // ---- LDS -> frag reads (conflict-free patterns) ----
    bf16x8 kf[4], vlo[2], vhi[2];
    #pragma unroll
    for (int t = 0; t < 4; ++t)
      kf[t] = __builtin_bit_cast(bf16x8, *(const uint4*)(kb + (16*t + r) * 64 + g * 16));
    #pragma unroll
    for (int c = 0; c < 2; ++c) {
      const int swz = ((4*c + g) ^ (r & 7)) * 16;
      vlo[c] = __builtin_bit_cast(bf16x8, *(const uint4*)(vb + r * 128 + swz));
      vhi[c] = __builtin_bit_cast(bf16x8, *(const uint4*)(vb + (16 + r) * 128 + swz));
    }

    #pragma unroll
    for (int q = 0; q < 4; ++q) {
      // ---- QK^T: st[t] = S^T[j=16t+4g+u][i=i_base+16q+r] ----
      f32x4 st[4];
      __builtin_amdgcn_s_setprio(1);
      #pragma unroll
      for (int t = 0; t < 4; ++t)
        st[t] = __builtin_amdgcn_mfma_f32_16x16x32_bf16(kf[t], qf[q], zero, 0, 0, 0);
      __builtin_amdgcn_s_setprio(0);

      // ---- online softmax (16 values per lane, all for ONE i) ----
      float m = -3.0e38f;
      #pragma unroll
      for (int t = 0; t < 4; ++t)
        m = fmaxf(m, fmaxf(fmaxf(st[t][0], st[t][1]), fmaxf(st[t][2], st[t][3])));
      m = fmaxf(m, __shfl_xor(m, 16));
      m = fmaxf(m, __shfl_xor(m, 32));

      const bool skip = __all(m - mrun[q] <= 8.0f);
      const float m_new = skip ? mrun[q] : fmaxf(mrun[q], m);

      float ps = 0.f;
      u32 wpk[4][2];
      #pragma unroll
      for (int t = 0; t < 4; ++t) {
        const float p0 = fast_exp2(st[t][0] - m_new);
        const float p1 = fast_exp2(st[t][1] - m_new);
        const float p2 = fast_exp2(st[t][2] - m_new);
        const float p3 = fast_exp2(st[t][3] - m_new);
        ps += (p0 + p1) + (p2 + p3);
        asm("v_cvt_pk_bf16_f32 %0, %1, %2" : "=v"(wpk[t][0]) : "v"(p0), "v"(p1));
        asm("v_cvt_pk_bf16_f32 %0, %1, %2" : "=v"(wpk[t][1]) : "v"(p2), "v"(p3));
      }
      ps += __shfl_xor(ps, 16);
      ps += __shfl_xor(ps, 32);
      if (skip) {
        lrun[q] += ps;
      } else {
        const float alpha = fast_exp2(mrun[q] - m_new);
        lrun[q] = lrun[q] * alpha + ps;
        mrun[q] = m_new;
        accL[q] *= alpha;
        accH[q] *= alpha;
      }

      // ---- in-register P^T -> B-frag route (HW-validated in R5) ----
      uint4 pr[2];
      #pragma unroll
      for (int c = 0; c < 2; ++c) {
        #pragma unroll
        for (int v = 0; v < 2; ++v) {
          u32 a = wpk[2*c + 0][v];
          u32 b = wpk[2*c + 1][v];
          asm("v_permlane32_swap_b32 %0, %1" : "+v"(a), "+v"(b));
          asm("v_permlane16_swap_b32 %0, %1" : "+v"(a), "+v"(b));
          pr[c][0 + v] = a;
          pr[c][2 + v] = b;
        }
      }

      // ---- PV: O^T += mfma(V^T, P) ----
      __builtin_amdgcn_s_setprio(1);
      #pragma unroll
      for (int c = 0; c < 2; ++c) {
        const bf16x8 pf = __builtin_bit_cast(bf16x8, pr[c]);
        accL[q] = __builtin_amdgcn_mfma_f32_16x16x32_bf16(vlo[c], pf, accL[q], 0, 0, 0);
        accH[q] = __builtin_amdgcn_mfma_f32_16x16x32_bf16(vhi[c], pf, accH[q], 0, 0, 0);
      }
      __builtin_amdgcn_s_setprio(0);
    }
  }

  // A^T[d][i] store (unnormalized)
  const size_t obase = ((size_t)(split*8 + bh)) * DIMH * NTOK;
  #pragma unroll
  for (int q = 0; q < 4; ++q) {
    float* ad = Apart + obase + i_base + 16*q + r;
    #pragma unroll
    for (int u = 0; u < 4; ++u) {
      ad[(size_t)(4*g + u) * NTOK]      = accL[q][u];
      ad[(size_t)(16 + 4*g + u) * NTOK] = accH[q][u];
    }
  }
  float* mlb = ml + ((size_t)(split*8 + bh) * 2) * NTOK;
  #pragma unroll
  for (int q = 0; q < 4; ++q) {
    const int i = i_base + 16*q + r;
    if (g == 0) mlb[i]        = mrun[q];
    if (g == 1) mlb[NTOK + i] = lrun[q];
  }
}

// ===================== Kernel C: fused split-combine + output projection =====================
template<int NS>
__global__ __launch_bounds__(256)
void out_proj_combine(const float* __restrict__ Apart, const float* __restrict__ ml,
                      const float* __restrict__ w, const float* __restrict__ bias,
                      float* __restrict__ out)
{
  __shared__ float xs[128][64];
  __shared__ float wt[128][64];
  __shared__ alignas(16) float wls[4][NS][64];
  const int tid = threadIdx.x;
  const int n0 = blockIdx.x * 64;
  const int o0 = blockIdx.y * 64;
  const int b  = blockIdx.z;

  { // combine weights: thread -> (h = tid>>6, n = tid&63)
    const int h = tid >> 6, n_l = tid & 63;
    const int bh = b*4 + h;
    float m[NS], l[NS], wv[NS];
    #pragma unroll
    for (int s = 0; s < NS; ++s) {
      const float* mlb = ml + ((size_t)(s*8 + bh) * 2) * NTOK;
      m[s] = mlb[n0 + n_l];
      l[s] = mlb[NTOK + n0 + n_l];
    }
    float mx = m[0];
    #pragma unroll
    for (int s = 1; s < NS; ++s) mx = fmaxf(mx, m[s]);
    float L = 0.f;
    #pragma unroll
    for (int s = 0; s < NS; ++s) { wv[s] = fast_exp2(m[s] - mx); L += wv[s] * l[s]; }
    const float inv = 1.0f / L;
    #pragma unroll
    for (int s = 0; s < NS; ++s) wls[h][s][n_l] = wv[s] * inv;
  }
  { // stage w tile transposed: wt[c][o_local]
    const int o_l = tid & 63, q4 = tid >> 6;
    const float* wrow = w + (size_t)(o0 + o_l) * CH;
    #pragma unroll
    for (int p = 0; p < 8; ++p) {
      const int c4 = p * 4 + q4;
      const float4 v4 = *(const float4*)(wrow + c4 * 4);
      wt[c4*4+0][o_l] = v4.x;
      wt[c4*4+1][o_l] = v4.y;
      wt[c4*4+2][o_l] = v4.z;
      wt[c4*4+3][o_l] = v4.w;
    }
  }
  __syncthreads();

  { // stage combined x tile [128 c][64 n]
    const int f4 = tid & 15, c0 = tid >> 4;
    #pragma unroll
    for (int p = 0; p < 8; ++p) {
      const int c = p * 16 + c0;
      const int h = c >> 5, d = c & 31;
      f32x4 acc = {0.f, 0.f, 0.f, 0.f};
      #pragma unroll
      for (int s = 0; s < NS; ++s) {
        const f32x4 a = *(const f32x4*)(Apart +
            ((size_t)((s*8 + b*4 + h) * DIMH + d)) * NTOK + n0 + f4 * 4);
        const f32x4 ww = *(const f32x4*)&wls[h][s][f4 * 4];
        acc += a * ww;
      }
      *(f32x4*)&xs[c][f4 * 4] = acc;
    }
  }
  __syncthreads();

  const int tx = tid & 15, ty = tid >> 4;
  float acc[4][4] = {};
  for (int c = 0; c < 128; ++c) {
    const float4 xv = *(const float4*)&xs[c][tx*4];
    const float4 wv = *(const float4*)&wt[c][ty*4];
    const float xa[4] = {xv.x, xv.y, xv.z, xv.w};
    const float wa[4] = {wv.x, wv.y, wv.z, wv.w};
    #pragma unroll
    for (int io = 0; io < 4; ++io)
      #pragma unroll
      for (int in = 0; in < 4; ++in)
        acc[io][in] += wa[io] * xa[in];
  }

  #pragma unroll
  for (int io = 0; io < 4; ++io) {
    const int o = o0 + ty*4 + io;
    const float bv = bias[o];
    float4 res = {acc[io][0]+bv, acc[io][1]+bv, acc[io][2]+bv, acc[io][3]+bv};
    *(float4*)(out + ((size_t)b * CH + o) * NTOK + n0 + tx*4) = res;
  }
}

extern "C" void kernel_launch(void* const* d_in, const int* in_sizes, int n_in,
                              void* d_out, int out_size, void* d_ws, size_t ws_size,
                              hipStream_t stream)
{
  const float* x     = (const float*)d_in[0];
  const float* w_qkv = (const float*)d_in[1];
  const float* w_out = (const float*)d_in[2];
  const float* b_out = (const float*)d_in[3];
  float* out = (float*)d_out;

  const size_t MB = 1024 * 1024;
  const size_t KB = 1024;
  // need: 6MB (qkv) + nsplit*(4MB Apart + 256KB ml)
  int nsplit = 1;
  if      (ws_size >= 6*MB + 8*(4*MB + 256*KB)) nsplit = 8;
  else if (ws_size >= 6*MB + 4*(4*MB + 256*KB)) nsplit = 4;
  else if (ws_size >= 6*MB + 2*(4*MB + 256*KB)) nsplit = 2;

  char* ws = (char*)d_ws;
  bf16_t* qs    = (bf16_t*)(ws);
  bf16_t* ks    = (bf16_t*)(ws + 2*MB);
  bf16_t* vs    = (bf16_t*)(ws + 4*MB);
  float*  Apart = (float*) (ws + 6*MB);
  float*  ml    = (float*) (ws + 6*MB + (size_t)nsplit*4*MB);

  qkv_proj<<<dim3(64, 6, 2), 256, 0, stream>>>(x, w_qkv, qs, ks, vs);
  if (nsplit == 8) {
    attn_fwd<8><<<dim3(8, 16, 8), 256, 0, stream>>>(qs, ks, vs, Apart, ml);
    out_proj_combine<8><<<dim3(64, 2, 2), 256, 0, stream>>>(Apart, ml, w_out, b_out, out);
  } else if (nsplit == 4) {
    attn_fwd<16><<<dim3(8, 16, 4), 256, 0, stream>>>(qs, ks, vs, Apart, ml);
    out_proj_combine<4><<<dim3(64, 2, 2), 256, 0, stream>>>(Apart, ml, w_out, b_out, out);
  } else if (nsplit == 2) {
    attn_fwd<32><<<dim3(8, 16, 2), 256, 0, stream>>>(qs, ks, vs, Apart, ml);
    out_proj_combine<2><<<dim3(64, 2, 2), 256, 0, stream>>>(Apart, ml, w_out, b_out, out);
  } else {
    attn_fwd<64><<<dim3(8, 16, 1), 256, 0, stream>>>(qs, ks, vs, Apart, ml);
    out_proj_combine<1><<<dim3(64, 2, 2), 256, 0, stream>>>(Apart, ml, w_out, b_out, out);
  }
}